// Round 1
// baseline (1327.403 us; speedup 1.0000x reference)
//
#include <hip/hip_runtime.h>
#include <math.h>

#define IND  64
#define OUTD 101

__global__ __launch_bounds__(64) void density_kernel(
    const float* __restrict__ t,
    const float* __restrict__ x,
    const float* __restrict__ weight,
    const float* __restrict__ bias,
    const int*   __restrict__ num_grid,
    float* __restrict__ out1,
    float* __restrict__ out_interp,
    int n_rows, int n_blocks)
{
    const int lane = threadIdx.x;      // 0..63, lane == column slot A
    const int jB   = lane + 64;        // column slot B (may be >= OUTD)
    const float ngf = (float)num_grid[0];

    // Persistent weight columns in VGPRs (loaded once, reused for ~500 rows).
    float w0[IND], w1[IND];
#pragma unroll
    for (int k = 0; k < IND; ++k) {
        w0[k] = weight[k * OUTD + lane];
        w1[k] = (jB < OUTD) ? weight[k * OUTD + jB] : 0.0f;
    }
    const float b0 = bias[lane];
    const float b1 = (jB < OUTD) ? bias[jB] : -INFINITY;  // exp -> 0, softmax unaffected

    for (int row = blockIdx.x; row < n_rows; row += n_blocks) {
        // x row is wave-uniform -> scalar loads
        const float* xr = x + (size_t)row * IND;
        float acc0 = b0, acc1 = b1;
#pragma unroll
        for (int k = 0; k < IND; ++k) {
            const float xk = xr[k];
            acc0 = fmaf(xk, w0[k], acc0);
            acc1 = fmaf(xk, w1[k], acc1);
        }

        // wave-wide softmax over the 101 (padded to 128) logits
        float m = fmaxf(acc0, acc1);
#pragma unroll
        for (int s = 32; s > 0; s >>= 1) m = fmaxf(m, __shfl_xor(m, s, 64));
        float p0 = __expf(acc0 - m);
        float p1 = __expf(acc1 - m);   // 0 for padded columns (acc1 = -inf)
        float ssum = p0 + p1;
#pragma unroll
        for (int s = 32; s > 0; s >>= 1) ssum += __shfl_xor(ssum, s, 64);
        float inv = __builtin_amdgcn_rcpf(ssum);
        inv = inv * (2.0f - ssum * inv);   // one Newton step -> ~fp32 exact
        p0 *= inv;
        p1 *= inv;

        // coalesced out1 row store
        float* orow = out1 + (size_t)row * OUTD;
        orow[lane] = p0;
        if (jB < OUTD) orow[jB] = p1;

        // data-dependent dual gather + lerp (indices wave-uniform)
        const float tB    = t[row] * ngf;
        const float U     = ceilf(tB);
        const float inter = 1.0f - (U - tB);
        float L = U - 1.0f;
        if (L < 0.0f) L += 1.0f;
        const int Li = (int)L;
        const int Ui = (int)U;
        const float srcL = (Li >= 64) ? p1 : p0;   // uniform select
        const float Lval = __shfl(srcL, Li & 63, 64);
        const float srcU = (Ui >= 64) ? p1 : p0;
        const float Uval = __shfl(srcU, Ui & 63, 64);
        if (lane == 0) out_interp[row] = Lval + (Uval - Lval) * inter;
    }
}

extern "C" void kernel_launch(void* const* d_in, const int* in_sizes, int n_in,
                              void* d_out, int out_size, void* d_ws, size_t ws_size,
                              hipStream_t stream) {
    const float* t  = (const float*)d_in[0];
    const float* x  = (const float*)d_in[1];
    const float* w  = (const float*)d_in[2];
    const float* b  = (const float*)d_in[3];
    const int*   ng = (const int*)d_in[4];
    const int n_rows = in_sizes[0];

    float* out1       = (float*)d_out;
    float* out_interp = out1 + (size_t)n_rows * OUTD;

    // ~170 VGPR -> 2 waves/SIMD -> 8 waves/CU; 2048 one-wave blocks fill 256 CUs
    const int n_blocks = 2048;
    density_kernel<<<dim3(n_blocks), dim3(64), 0, stream>>>(
        t, x, w, b, ng, out1, out_interp, n_rows, n_blocks);
}

// Round 2
// 960.936 us; speedup vs baseline: 1.3814x; 1.3814x over previous
//
#include <hip/hip_runtime.h>
#include <math.h>

#define IND  64
#define OUTD 101

// (64, 3): min 3 waves/EU -> VGPR cap ~170, enough to keep the 128
// weight floats RESIDENT in VGPRs (round 1: default heuristic capped at
// 76 VGPR and rematerialized weight loads from global every row).
__global__ __launch_bounds__(64, 3) void density_kernel(
    const float* __restrict__ t,
    const float* __restrict__ x,
    const float* __restrict__ weight,
    const float* __restrict__ bias,
    const int*   __restrict__ num_grid,
    float* __restrict__ out1,
    float* __restrict__ out_interp,
    int n_rows, int n_blocks)
{
    const int lane = threadIdx.x;      // 0..63, lane == column slot A
    const int jB   = lane + 64;        // column slot B (may be >= OUTD)
    const float ngf = (float)num_grid[0];

    // Persistent weight columns in VGPRs (loaded once, reused for ~330 rows).
    float w0[IND], w1[IND];
#pragma unroll
    for (int k = 0; k < IND; ++k) {
        w0[k] = weight[k * OUTD + lane];
        w1[k] = (jB < OUTD) ? weight[k * OUTD + jB] : 0.0f;
    }
    const float b0 = bias[lane];
    const float b1 = (jB < OUTD) ? bias[jB] : -INFINITY;  // exp -> 0, softmax unaffected

    for (int row = blockIdx.x; row < n_rows; row += n_blocks) {
        // x row is wave-uniform -> scalar (s_load) reads through SGPRs
        const float* xr = x + (size_t)row * IND;
        float acc0 = b0, acc1 = b1;
#pragma unroll
        for (int k = 0; k < IND; ++k) {
            const float xk = xr[k];
            acc0 = fmaf(xk, w0[k], acc0);
            acc1 = fmaf(xk, w1[k], acc1);
        }

        // wave-wide softmax over the 101 (padded to 128) logits
        float m = fmaxf(acc0, acc1);
#pragma unroll
        for (int s = 32; s > 0; s >>= 1) m = fmaxf(m, __shfl_xor(m, s, 64));
        float p0 = __expf(acc0 - m);
        float p1 = __expf(acc1 - m);   // 0 for padded columns (acc1 = -inf)
        float ssum = p0 + p1;
#pragma unroll
        for (int s = 32; s > 0; s >>= 1) ssum += __shfl_xor(ssum, s, 64);
        float inv = __builtin_amdgcn_rcpf(ssum);
        inv = inv * (2.0f - ssum * inv);   // one Newton step -> ~fp32 exact
        p0 *= inv;
        p1 *= inv;

        // coalesced out1 row store
        float* orow = out1 + (size_t)row * OUTD;
        orow[lane] = p0;
        if (jB < OUTD) orow[jB] = p1;

        // data-dependent dual gather + lerp (indices wave-uniform)
        const float tB    = t[row] * ngf;
        const float U     = ceilf(tB);
        const float inter = 1.0f - (U - tB);
        float L = U - 1.0f;
        if (L < 0.0f) L += 1.0f;
        const int Li = (int)L;
        const int Ui = (int)U;
        const float srcL = (Li >= 64) ? p1 : p0;   // uniform select
        const float Lval = __shfl(srcL, Li & 63, 64);
        const float srcU = (Ui >= 64) ? p1 : p0;
        const float Uval = __shfl(srcU, Ui & 63, 64);
        if (lane == 0) out_interp[row] = Lval + (Uval - Lval) * inter;
    }
}

extern "C" void kernel_launch(void* const* d_in, const int* in_sizes, int n_in,
                              void* d_out, int out_size, void* d_ws, size_t ws_size,
                              hipStream_t stream) {
    const float* t  = (const float*)d_in[0];
    const float* x  = (const float*)d_in[1];
    const float* w  = (const float*)d_in[2];
    const float* b  = (const float*)d_in[3];
    const int*   ng = (const int*)d_in[4];
    const int n_rows = in_sizes[0];

    float* out1       = (float*)d_out;
    float* out_interp = out1 + (size_t)n_rows * OUTD;

    // 3 waves/SIMD x 4 SIMD x 256 CU = 3072 one-wave blocks
    const int n_blocks = 3072;
    density_kernel<<<dim3(n_blocks), dim3(64), 0, stream>>>(
        t, x, w, b, ng, out1, out_interp, n_rows, n_blocks);
}